// Round 3
// baseline (1603.120 us; speedup 1.0000x reference)
//
#include <hip/hip_runtime.h>

#define TPB 256
constexpr float EPSV = 1e-5f;

// =================== CSR build (counting sort of edges by col) ===================

__global__ void k_hist(const int* __restrict__ col, int* __restrict__ cnt, int E) {
  int e = blockIdx.x * blockDim.x + threadIdx.x;
  if (e < E) atomicAdd(&cnt[col[e]], 1);
}

#define SCAN_T 512
#define SCAN_E 8
#define SCAN_BLK (SCAN_T * SCAN_E)  // 4096

__global__ void k_scan_partial(const int* __restrict__ cnt, int* __restrict__ bsum, int N) {
  __shared__ int red[SCAN_T];
  int tid = threadIdx.x;
  int base = blockIdx.x * SCAN_BLK + tid * SCAN_E;
  int s = 0;
#pragma unroll
  for (int k = 0; k < SCAN_E; ++k) {
    int i = base + k;
    if (i < N) s += cnt[i];
  }
  red[tid] = s;
  __syncthreads();
  for (int off = SCAN_T / 2; off > 0; off >>= 1) {
    if (tid < off) red[tid] += red[tid + off];
    __syncthreads();
  }
  if (tid == 0) bsum[blockIdx.x] = red[0];
}

__global__ void k_scan_bsum(int* __restrict__ bsum, int* __restrict__ ptrN, int nb, int E) {
  if (threadIdx.x == 0) {
    int run = 0;
    for (int b = 0; b < nb; ++b) { int v = bsum[b]; bsum[b] = run; run += v; }
    *ptrN = E;  // ptr[N]
  }
}

__global__ void k_scan_final(const int* __restrict__ cnt, const int* __restrict__ bsum,
                             int* __restrict__ ptr, int* __restrict__ cur, int N) {
  __shared__ int red[SCAN_T];
  int tid = threadIdx.x;
  int base = blockIdx.x * SCAN_BLK + tid * SCAN_E;
  int loc[SCAN_E];
  int s = 0;
#pragma unroll
  for (int k = 0; k < SCAN_E; ++k) {
    int i = base + k;
    int v = (i < N) ? cnt[i] : 0;
    loc[k] = s;
    s += v;
  }
  red[tid] = s;
  __syncthreads();
  for (int off = 1; off < SCAN_T; off <<= 1) {
    int v = (tid >= off) ? red[tid - off] : 0;
    __syncthreads();
    red[tid] += v;
    __syncthreads();
  }
  int tbase = bsum[blockIdx.x] + (tid > 0 ? red[tid - 1] : 0);
#pragma unroll
  for (int k = 0; k < SCAN_E; ++k) {
    int i = base + k;
    if (i < N) { int v = tbase + loc[k]; ptr[i] = v; cur[i] = v; }
  }
}

__global__ void k_fill(const int* __restrict__ row, const int* __restrict__ col,
                       const float* __restrict__ w, int* __restrict__ cur,
                       uint2* __restrict__ pk, int E) {
  int e = blockIdx.x * blockDim.x + threadIdx.x;
  if (e < E) {
    int pos = atomicAdd(&cur[col[e]], 1);
    pk[pos] = make_uint2((unsigned)row[e], __float_as_uint(w[e]));
  }
}

// deg[i] = 1 (self-loop) + sum of incoming weights; dinv = rsqrt
__global__ void k_degdinv(const uint2* __restrict__ pk, const int* __restrict__ ptr,
                          float* __restrict__ dinv, int N) {
  int i = blockIdx.x * blockDim.x + threadIdx.x;
  if (i >= N) return;
  int p0 = ptr[i], p1 = ptr[i + 1];
  float d = 1.0f;
  for (int p = p0; p < p1; ++p) d += __uint_as_float(pk[p].y);
  dinv[i] = d > 0.0f ? rsqrtf(fmaxf(d, EPSV)) : 0.0f;
}

// overwrite packed weight with norm = dinv[row]*w*dinv[col]
__global__ void k_nrmcsr(uint2* __restrict__ pk, const int* __restrict__ ptr,
                         const float* __restrict__ dinv, int N) {
  int i = blockIdx.x * blockDim.x + threadIdx.x;
  if (i >= N) return;
  int p0 = ptr[i], p1 = ptr[i + 1];
  float dvc = dinv[i];
  for (int p = p0; p < p1; ++p) {
    uint2 e = pk[p];
    pk[p].y = __float_as_uint(dinv[e.x] * __uint_as_float(e.y) * dvc);
  }
}

// =================== per-layer transform: t = relu(BN(in)) @ W ===================
// 8 nodes per block, 32 lanes per node (lane = output channel).

template <int IN, bool BN>
__global__ void k_transform(const float* __restrict__ in, const float* __restrict__ W,
                            const float* __restrict__ ss, float* __restrict__ t, int N) {
  __shared__ float Ws[IN * 32];
  __shared__ float hs[8 * IN];
  const int tid = threadIdx.x;
  const int n0 = blockIdx.x * 8;
  for (int k = tid; k < IN * 32; k += TPB) Ws[k] = W[k];
  for (int k = tid; k < 8 * IN; k += TPB) {
    int node = n0 + k / IN;
    float v = 0.0f;
    if (node < N) {
      v = in[n0 * IN + k];
      if constexpr (BN) {
        int c = k % IN;  // IN == 32 when BN
        v = fmaxf(v * ss[c] + ss[32 + c], 0.0f);
      }
    }
    hs[k] = v;
  }
  __syncthreads();
  const int j = tid >> 5, c = tid & 31;
  const int node = n0 + j;
  if (node < N) {
    float acc = 0.0f;
#pragma unroll
    for (int k = 0; k < IN; ++k) acc += hs[j * IN + k] * Ws[k * 32 + c];
    t[(size_t)node * 32 + c] = acc;
  }
}

// =================== CSR gather: out[n] = dinv[n]^2*t[n] + sum nrm*t[row] ===================

__global__ void k_gather(const uint2* __restrict__ pk, const int* __restrict__ ptr,
                         const float* __restrict__ dinv, const float* __restrict__ t,
                         float* __restrict__ out, int N) {
  const int tid = threadIdx.x;
  const int j = tid >> 5, c = tid & 31;
  const int n = blockIdx.x * 8 + j;
  if (n >= N) return;
  const int p0 = ptr[n], p1 = ptr[n + 1];
  const float dvn = dinv[n];
  float acc = dvn * dvn * t[(size_t)n * 32 + c];
  int p = p0;
  // unroll by 2 to keep more loads in flight
  for (; p + 1 < p1; p += 2) {
    uint2 e0 = pk[p], e1 = pk[p + 1];
    float v0 = t[(size_t)e0.x * 32 + c];
    float v1 = t[(size_t)e1.x * 32 + c];
    acc += __uint_as_float(e0.y) * v0;
    acc += __uint_as_float(e1.y) * v1;
  }
  if (p < p1) {
    uint2 e0 = pk[p];
    acc += __uint_as_float(e0.y) * t[(size_t)e0.x * 32 + c];
  }
  out[(size_t)n * 32 + c] = acc;
}

// =================== BN stats over node axis ===================

__global__ void k_stats(const float* __restrict__ x, float* __restrict__ gstats, int total) {
  __shared__ float ls[TPB], lq[TPB];
  int tid = threadIdx.x;
  float s = 0.f, q = 0.f;
  for (int idx = blockIdx.x * TPB + tid; idx < total; idx += gridDim.x * TPB) {
    float v = x[idx];
    s += v;
    q += v * v;
  }
  ls[tid] = s; lq[tid] = q;
  __syncthreads();
  for (int off = TPB / 2; off >= 32; off >>= 1) {
    if (tid < off) { ls[tid] += ls[tid + off]; lq[tid] += lq[tid + off]; }
    __syncthreads();
  }
  if (tid < 32) {
    unsafeAtomicAdd(&gstats[tid], ls[tid]);
    unsafeAtomicAdd(&gstats[32 + tid], lq[tid]);
  }
}

__global__ void k_bnfin(const float* __restrict__ gstats, const float* __restrict__ gamma,
                        const float* __restrict__ beta, float* __restrict__ ss, float invN) {
  int c = threadIdx.x;
  if (c < 32) {
    float m = gstats[c] * invN;
    float v = gstats[32 + c] * invN - m * m;
    float sc = gamma[c] * rsqrtf(v + EPSV);
    ss[c] = sc;
    ss[32 + c] = beta[c] - m * sc;
  }
}

// =================== global add pool (batch is sorted) ===================

__global__ void k_pool(const float* __restrict__ h, const int* __restrict__ batch,
                       const float* __restrict__ b3, float* __restrict__ pool, int N) {
  __shared__ float red[TPB];
  int g = blockIdx.x, tid = threadIdx.x;
  int lo = 0, hi = N;
  while (lo < hi) { int mid = (lo + hi) >> 1; if (batch[mid] < g) lo = mid + 1; else hi = mid; }
  int start = lo;
  hi = N;
  while (lo < hi) { int mid = (lo + hi) >> 1; if (batch[mid] < g + 1) lo = mid + 1; else hi = mid; }
  int end = lo;
  int j = tid >> 5, c = tid & 31;
  float acc = 0.f;
  for (int i = start + j; i < end; i += 8) acc += h[(size_t)i * 32 + c];
  red[tid] = acc;
  __syncthreads();
  for (int off = 128; off >= 32; off >>= 1) {
    if (tid < off) red[tid] += red[tid + off];
    __syncthreads();
  }
  if (tid < 32) pool[g * 32 + tid] = red[tid] + (float)(end - start) * b3[tid];
}

// =================== final MLP ===================
// 512 threads, one graph-row per thread. ALL per-thread arrays statically
// indexed (stay in VGPRs — dynamic indexing forced scratch spill last round:
// 244 us, VALUBusy 0.009%). BN stats via 64-lane shfl_xor butterfly + one
// LDS atomic per wave per channel.

__global__ void k_mlp(const float* __restrict__ pool, const float* __restrict__ Wm0,
                      const float* __restrict__ bm0, const float* __restrict__ bng,
                      const float* __restrict__ bnb, const float* __restrict__ Wm1,
                      const float* __restrict__ bm1, float* __restrict__ out) {
  __shared__ float Ws[32 * 32];
  __shared__ float lsum[32], lsq[32];
  __shared__ float sc[32], sh[32];
  const int tid = threadIdx.x;  // 0..511 == graph row
  for (int k = tid; k < 1024; k += 512) Ws[k] = Wm0[k];
  if (tid < 32) { lsum[tid] = 0.f; lsq[tid] = 0.f; }
  __syncthreads();

  float p[32], z[32];
#pragma unroll
  for (int k = 0; k < 32; ++k) p[k] = pool[tid * 32 + k];
#pragma unroll
  for (int c = 0; c < 32; ++c) {
    float a = bm0[c];
#pragma unroll
    for (int k = 0; k < 32; ++k) a += p[k] * Ws[k * 32 + c];
    z[c] = a;
  }

  const int lane = tid & 63;
#pragma unroll
  for (int c = 0; c < 32; ++c) {
    float sv = z[c];
    float qv = z[c] * z[c];
#pragma unroll
    for (int m = 1; m < 64; m <<= 1) {
      sv += __shfl_xor(sv, m, 64);
      qv += __shfl_xor(qv, m, 64);
    }
    if (lane == 0) {
      atomicAdd(&lsum[c], sv);
      atomicAdd(&lsq[c], qv);
    }
  }
  __syncthreads();
  if (tid < 32) {
    float m = lsum[tid] / 512.0f;
    float v = lsq[tid] / 512.0f - m * m;
    float s = bng[tid] * rsqrtf(v + EPSV);
    sc[tid] = s;
    sh[tid] = bnb[tid] - m * s;
  }
  __syncthreads();

  float o0 = bm1[0], o1 = bm1[1];
#pragma unroll
  for (int c = 0; c < 32; ++c) {
    float hc = fmaxf(z[c] * sc[c] + sh[c], 0.f);
    o0 += hc * Wm1[c * 2 + 0];
    o1 += hc * Wm1[c * 2 + 1];
  }
  out[tid * 2 + 0] = o0;
  out[tid * 2 + 1] = o1;
}

// =================== launch ===================

extern "C" void kernel_launch(void* const* d_in, const int* in_sizes, int n_in,
                              void* d_out, int out_size, void* d_ws, size_t ws_size,
                              hipStream_t stream) {
  const float* x     = (const float*)d_in[0];
  const int*   ei    = (const int*)d_in[1];
  const float* ea    = (const float*)d_in[2];
  const int*   batch = (const int*)d_in[3];
  const float* W0    = (const float*)d_in[4];
  const float* W1    = (const float*)d_in[6];
  const float* W2    = (const float*)d_in[8];
  const float* W3    = (const float*)d_in[10];
  const float* b3    = (const float*)d_in[11];
  const float* bng   = (const float*)d_in[12];  // [3,32]
  const float* bnb   = (const float*)d_in[13];
  const float* Wm0   = (const float*)d_in[14];
  const float* bm0   = (const float*)d_in[15];
  const float* bnmg  = (const float*)d_in[16];
  const float* bnmb  = (const float*)d_in[17];
  const float* Wm1   = (const float*)d_in[18];
  const float* bm1   = (const float*)d_in[19];
  float* out = (float*)d_out;

  const int N = in_sizes[3];
  const int E = in_sizes[2];
  const int* row = ei;
  const int* col = ei + E;

  char* wsb = (char*)d_ws;
  auto alloc = [&](size_t bytes) { char* p = wsb; wsb += (bytes + 255) & ~size_t(255); return p; };
  int*   cnt  = (int*)alloc((size_t)(N + 1) * 4);
  int*   ptr  = (int*)alloc((size_t)(N + 1) * 4);
  int*   cur  = (int*)alloc((size_t)N * 4);
  int*   bsum = (int*)alloc(1024 * 4);
  uint2* pk   = (uint2*)alloc((size_t)E * 8);
  float* dinv = (float*)alloc((size_t)N * 4);
  float* B0   = (float*)alloc((size_t)N * 32 * 4);
  float* B1   = (float*)alloc((size_t)N * 32 * 4);
  float* stats = (float*)alloc(3 * 64 * 4);
  float* ss    = (float*)alloc(3 * 64 * 4);
  float* pool  = (float*)alloc(512 * 32 * 4);

  hipMemsetAsync(cnt, 0, (size_t)N * 4, stream);
  hipMemsetAsync(stats, 0, 3 * 64 * 4, stream);

  const int nb_n = (N + TPB - 1) / TPB;
  const int nb_e = (E + TPB - 1) / TPB;
  const int nb_t = (N + 7) / 8;
  const int nb_scan = (N + SCAN_BLK - 1) / SCAN_BLK;
  const int total32 = N * 32;
  const float invN = 1.0f / (float)N;

  // ---- CSR build ----
  k_hist<<<nb_e, TPB, 0, stream>>>(col, cnt, E);
  k_scan_partial<<<nb_scan, SCAN_T, 0, stream>>>(cnt, bsum, N);
  k_scan_bsum<<<1, 1, 0, stream>>>(bsum, ptr + N, nb_scan, E);
  k_scan_final<<<nb_scan, SCAN_T, 0, stream>>>(cnt, bsum, ptr, cur, N);
  k_fill<<<nb_e, TPB, 0, stream>>>(row, col, ea, cur, pk, E);
  k_degdinv<<<nb_n, TPB, 0, stream>>>(pk, ptr, dinv, N);
  k_nrmcsr<<<nb_n, TPB, 0, stream>>>(pk, ptr, dinv, N);

  // ---- layer 0 (x[N,7] @ W0) ----
  k_transform<7, false><<<nb_t, TPB, 0, stream>>>(x, W0, nullptr, B0, N);
  k_gather<<<nb_t, TPB, 0, stream>>>(pk, ptr, dinv, B0, B1, N);
  k_stats<<<1024, TPB, 0, stream>>>(B1, stats, total32);
  k_bnfin<<<1, 32, 0, stream>>>(stats, bng, bnb, ss, invN);

  // ---- layer 1 ----
  k_transform<32, true><<<nb_t, TPB, 0, stream>>>(B1, W1, ss, B0, N);
  k_gather<<<nb_t, TPB, 0, stream>>>(pk, ptr, dinv, B0, B1, N);
  k_stats<<<1024, TPB, 0, stream>>>(B1, stats + 64, total32);
  k_bnfin<<<1, 32, 0, stream>>>(stats + 64, bng + 32, bnb + 32, ss + 64, invN);

  // ---- layer 2 ----
  k_transform<32, true><<<nb_t, TPB, 0, stream>>>(B1, W2, ss + 64, B0, N);
  k_gather<<<nb_t, TPB, 0, stream>>>(pk, ptr, dinv, B0, B1, N);
  k_stats<<<1024, TPB, 0, stream>>>(B1, stats + 128, total32);
  k_bnfin<<<1, 32, 0, stream>>>(stats + 128, bng + 64, bnb + 64, ss + 128, invN);

  // ---- layer 3 (no BN on output) ----
  k_transform<32, true><<<nb_t, TPB, 0, stream>>>(B1, W3, ss + 128, B0, N);
  k_gather<<<nb_t, TPB, 0, stream>>>(pk, ptr, dinv, B0, B1, N);

  // ---- pool + MLP head ----
  k_pool<<<512, TPB, 0, stream>>>(B1, batch, b3, pool, N);
  k_mlp<<<1, 512, 0, stream>>>(pool, Wm0, bm0, bnmg, bnmb, Wm1, bm1, out);
}

// Round 4
// 1542.753 us; speedup vs baseline: 1.0391x; 1.0391x over previous
//
#include <hip/hip_runtime.h>

#define TPB 256
constexpr float EPSV = 1e-5f;

// =================== CSR build (counting sort of edges by col) ===================

__global__ void k_hist(const int* __restrict__ col, int* __restrict__ cnt, int E) {
  int e = blockIdx.x * blockDim.x + threadIdx.x;
  if (e < E) atomicAdd(&cnt[col[e]], 1);
}

#define SCAN_T 512
#define SCAN_E 8
#define SCAN_BLK (SCAN_T * SCAN_E)  // 4096

__global__ void k_scan_partial(const int* __restrict__ cnt, int* __restrict__ bsum, int N) {
  __shared__ int red[SCAN_T];
  int tid = threadIdx.x;
  int base = blockIdx.x * SCAN_BLK + tid * SCAN_E;
  int s = 0;
#pragma unroll
  for (int k = 0; k < SCAN_E; ++k) {
    int i = base + k;
    if (i < N) s += cnt[i];
  }
  red[tid] = s;
  __syncthreads();
  for (int off = SCAN_T / 2; off > 0; off >>= 1) {
    if (tid < off) red[tid] += red[tid + off];
    __syncthreads();
  }
  if (tid == 0) bsum[blockIdx.x] = red[0];
}

__global__ void k_scan_bsum(int* __restrict__ bsum, int* __restrict__ ptrN, int nb, int E) {
  if (threadIdx.x == 0) {
    int run = 0;
    for (int b = 0; b < nb; ++b) { int v = bsum[b]; bsum[b] = run; run += v; }
    *ptrN = E;  // ptr[N]
  }
}

__global__ void k_scan_final(const int* __restrict__ cnt, const int* __restrict__ bsum,
                             int* __restrict__ ptr, int* __restrict__ cur, int N) {
  __shared__ int red[SCAN_T];
  int tid = threadIdx.x;
  int base = blockIdx.x * SCAN_BLK + tid * SCAN_E;
  int loc[SCAN_E];
  int s = 0;
#pragma unroll
  for (int k = 0; k < SCAN_E; ++k) {
    int i = base + k;
    int v = (i < N) ? cnt[i] : 0;
    loc[k] = s;
    s += v;
  }
  red[tid] = s;
  __syncthreads();
  for (int off = 1; off < SCAN_T; off <<= 1) {
    int v = (tid >= off) ? red[tid - off] : 0;
    __syncthreads();
    red[tid] += v;
    __syncthreads();
  }
  int tbase = bsum[blockIdx.x] + (tid > 0 ? red[tid - 1] : 0);
#pragma unroll
  for (int k = 0; k < SCAN_E; ++k) {
    int i = base + k;
    if (i < N) { int v = tbase + loc[k]; ptr[i] = v; cur[i] = v; }
  }
}

__global__ void k_fill(const int* __restrict__ row, const int* __restrict__ col,
                       const float* __restrict__ w, int* __restrict__ cur,
                       uint2* __restrict__ pk, int E) {
  int e = blockIdx.x * blockDim.x + threadIdx.x;
  if (e < E) {
    int pos = atomicAdd(&cur[col[e]], 1);
    pk[pos] = make_uint2((unsigned)row[e], __float_as_uint(w[e]));
  }
}

// deg[i] = 1 (self-loop) + sum of incoming weights; dinv = rsqrt
__global__ void k_degdinv(const uint2* __restrict__ pk, const int* __restrict__ ptr,
                          float* __restrict__ dinv, int N) {
  int i = blockIdx.x * blockDim.x + threadIdx.x;
  if (i >= N) return;
  int p0 = ptr[i], p1 = ptr[i + 1];
  float d = 1.0f;
  for (int p = p0; p < p1; ++p) d += __uint_as_float(pk[p].y);
  dinv[i] = d > 0.0f ? rsqrtf(fmaxf(d, EPSV)) : 0.0f;
}

// overwrite packed weight with norm = dinv[row]*w*dinv[col]
__global__ void k_nrmcsr(uint2* __restrict__ pk, const int* __restrict__ ptr,
                         const float* __restrict__ dinv, int N) {
  int i = blockIdx.x * blockDim.x + threadIdx.x;
  if (i >= N) return;
  int p0 = ptr[i], p1 = ptr[i + 1];
  float dvc = dinv[i];
  for (int p = p0; p < p1; ++p) {
    uint2 e = pk[p];
    pk[p].y = __float_as_uint(dinv[e.x] * __uint_as_float(e.y) * dvc);
  }
}

// =================== per-layer transform: t = relu(BN(in)) @ W ===================
// 8 nodes per block, 32 lanes per node (lane = output channel).

template <int IN, bool BN>
__global__ void k_transform(const float* __restrict__ in, const float* __restrict__ W,
                            const float* __restrict__ ss, float* __restrict__ t, int N) {
  __shared__ float Ws[IN * 32];
  __shared__ float hs[8 * IN];
  const int tid = threadIdx.x;
  const int n0 = blockIdx.x * 8;
  for (int k = tid; k < IN * 32; k += TPB) Ws[k] = W[k];
  for (int k = tid; k < 8 * IN; k += TPB) {
    int node = n0 + k / IN;
    float v = 0.0f;
    if (node < N) {
      v = in[n0 * IN + k];
      if constexpr (BN) {
        int c = k % IN;  // IN == 32 when BN
        v = fmaxf(v * ss[c] + ss[32 + c], 0.0f);
      }
    }
    hs[k] = v;
  }
  __syncthreads();
  const int j = tid >> 5, c = tid & 31;
  const int node = n0 + j;
  if (node < N) {
    float acc = 0.0f;
#pragma unroll
    for (int k = 0; k < IN; ++k) acc += hs[j * IN + k] * Ws[k * 32 + c];
    t[(size_t)node * 32 + c] = acc;
  }
}

// =================== CSR gather: out[n] = dinv[n]^2*t[n] + sum nrm*t[row] ===================

__global__ void k_gather(const uint2* __restrict__ pk, const int* __restrict__ ptr,
                         const float* __restrict__ dinv, const float* __restrict__ t,
                         float* __restrict__ out, int N) {
  const int tid = threadIdx.x;
  const int j = tid >> 5, c = tid & 31;
  const int n = blockIdx.x * 8 + j;
  if (n >= N) return;
  const int p0 = ptr[n], p1 = ptr[n + 1];
  const float dvn = dinv[n];
  float acc = dvn * dvn * t[(size_t)n * 32 + c];
  int p = p0;
  // unroll by 2 to keep more loads in flight
  for (; p + 1 < p1; p += 2) {
    uint2 e0 = pk[p], e1 = pk[p + 1];
    float v0 = t[(size_t)e0.x * 32 + c];
    float v1 = t[(size_t)e1.x * 32 + c];
    acc += __uint_as_float(e0.y) * v0;
    acc += __uint_as_float(e1.y) * v1;
  }
  if (p < p1) {
    uint2 e0 = pk[p];
    acc += __uint_as_float(e0.y) * t[(size_t)e0.x * 32 + c];
  }
  out[(size_t)n * 32 + c] = acc;
}

// =================== BN stats over node axis ===================

__global__ void k_stats(const float* __restrict__ x, float* __restrict__ gstats, int total) {
  __shared__ float ls[TPB], lq[TPB];
  int tid = threadIdx.x;
  float s = 0.f, q = 0.f;
  for (int idx = blockIdx.x * TPB + tid; idx < total; idx += gridDim.x * TPB) {
    float v = x[idx];
    s += v;
    q += v * v;
  }
  ls[tid] = s; lq[tid] = q;
  __syncthreads();
  for (int off = TPB / 2; off >= 32; off >>= 1) {
    if (tid < off) { ls[tid] += ls[tid + off]; lq[tid] += lq[tid + off]; }
    __syncthreads();
  }
  if (tid < 32) {
    unsafeAtomicAdd(&gstats[tid], ls[tid]);
    unsafeAtomicAdd(&gstats[32 + tid], lq[tid]);
  }
}

__global__ void k_bnfin(const float* __restrict__ gstats, const float* __restrict__ gamma,
                        const float* __restrict__ beta, float* __restrict__ ss, float invN) {
  int c = threadIdx.x;
  if (c < 32) {
    float m = gstats[c] * invN;
    float v = gstats[32 + c] * invN - m * m;
    float sc = gamma[c] * rsqrtf(v + EPSV);
    ss[c] = sc;
    ss[32 + c] = beta[c] - m * sc;
  }
}

// =================== global add pool (batch is sorted) ===================

__global__ void k_pool(const float* __restrict__ h, const int* __restrict__ batch,
                       const float* __restrict__ b3, float* __restrict__ pool, int N) {
  __shared__ float red[TPB];
  int g = blockIdx.x, tid = threadIdx.x;
  int lo = 0, hi = N;
  while (lo < hi) { int mid = (lo + hi) >> 1; if (batch[mid] < g) lo = mid + 1; else hi = mid; }
  int start = lo;
  hi = N;
  while (lo < hi) { int mid = (lo + hi) >> 1; if (batch[mid] < g + 1) lo = mid + 1; else hi = mid; }
  int end = lo;
  int j = tid >> 5, c = tid & 31;
  float acc = 0.f;
  for (int i = start + j; i < end; i += 8) acc += h[(size_t)i * 32 + c];
  red[tid] = acc;
  __syncthreads();
  for (int off = 128; off >= 32; off >>= 1) {
    if (tid < off) red[tid] += red[tid + off];
    __syncthreads();
  }
  if (tid < 32) pool[g * 32 + tid] = red[tid] + (float)(end - start) * b3[tid];
}

// =================== final MLP ===================
// 512 threads, one graph-row per thread. __launch_bounds__(512) is load-bearing:
// without it hipcc assumes a 1024-thread block and caps the allocator at 64
// VGPRs -> the p[32]/z[32] arrays spill to scratch (observed: WRITE_SIZE
// 1.9 MB for a 4 KB-output kernel, 360 us, VALUBusy ~0). With 512 threads
// (8 waves, 2/SIMD) the cap is 256 VGPRs and everything stays in registers.

__global__ __launch_bounds__(512) void k_mlp(
    const float* __restrict__ pool, const float* __restrict__ Wm0,
    const float* __restrict__ bm0, const float* __restrict__ bng,
    const float* __restrict__ bnb, const float* __restrict__ Wm1,
    const float* __restrict__ bm1, float* __restrict__ out) {
  __shared__ float Ws[32 * 32];
  __shared__ float lsum[32], lsq[32];
  __shared__ float sc[32], sh[32];
  const int tid = threadIdx.x;  // 0..511 == graph row
  for (int k = tid; k < 1024; k += 512) Ws[k] = Wm0[k];
  if (tid < 32) { lsum[tid] = 0.f; lsq[tid] = 0.f; }
  __syncthreads();

  float p[32], z[32];
#pragma unroll
  for (int k = 0; k < 32; ++k) p[k] = pool[tid * 32 + k];
#pragma unroll
  for (int c = 0; c < 32; ++c) {
    float a = bm0[c];
#pragma unroll
    for (int k = 0; k < 32; ++k) a += p[k] * Ws[k * 32 + c];
    z[c] = a;
  }

  const int lane = tid & 63;
#pragma unroll
  for (int c = 0; c < 32; ++c) {
    float sv = z[c];
    float qv = z[c] * z[c];
#pragma unroll
    for (int m = 1; m < 64; m <<= 1) {
      sv += __shfl_xor(sv, m, 64);
      qv += __shfl_xor(qv, m, 64);
    }
    if (lane == 0) {
      atomicAdd(&lsum[c], sv);
      atomicAdd(&lsq[c], qv);
    }
  }
  __syncthreads();
  if (tid < 32) {
    float m = lsum[tid] / 512.0f;
    float v = lsq[tid] / 512.0f - m * m;
    float s = bng[tid] * rsqrtf(v + EPSV);
    sc[tid] = s;
    sh[tid] = bnb[tid] - m * s;
  }
  __syncthreads();

  float o0 = bm1[0], o1 = bm1[1];
#pragma unroll
  for (int c = 0; c < 32; ++c) {
    float hc = fmaxf(z[c] * sc[c] + sh[c], 0.f);
    o0 += hc * Wm1[c * 2 + 0];
    o1 += hc * Wm1[c * 2 + 1];
  }
  out[tid * 2 + 0] = o0;
  out[tid * 2 + 1] = o1;
}

// =================== launch ===================

extern "C" void kernel_launch(void* const* d_in, const int* in_sizes, int n_in,
                              void* d_out, int out_size, void* d_ws, size_t ws_size,
                              hipStream_t stream) {
  const float* x     = (const float*)d_in[0];
  const int*   ei    = (const int*)d_in[1];
  const float* ea    = (const float*)d_in[2];
  const int*   batch = (const int*)d_in[3];
  const float* W0    = (const float*)d_in[4];
  const float* W1    = (const float*)d_in[6];
  const float* W2    = (const float*)d_in[8];
  const float* W3    = (const float*)d_in[10];
  const float* b3    = (const float*)d_in[11];
  const float* bng   = (const float*)d_in[12];  // [3,32]
  const float* bnb   = (const float*)d_in[13];
  const float* Wm0   = (const float*)d_in[14];
  const float* bm0   = (const float*)d_in[15];
  const float* bnmg  = (const float*)d_in[16];
  const float* bnmb  = (const float*)d_in[17];
  const float* Wm1   = (const float*)d_in[18];
  const float* bm1   = (const float*)d_in[19];
  float* out = (float*)d_out;

  const int N = in_sizes[3];
  const int E = in_sizes[2];
  const int* row = ei;
  const int* col = ei + E;

  char* wsb = (char*)d_ws;
  auto alloc = [&](size_t bytes) { char* p = wsb; wsb += (bytes + 255) & ~size_t(255); return p; };
  int*   cnt  = (int*)alloc((size_t)(N + 1) * 4);
  int*   ptr  = (int*)alloc((size_t)(N + 1) * 4);
  int*   cur  = (int*)alloc((size_t)N * 4);
  int*   bsum = (int*)alloc(1024 * 4);
  uint2* pk   = (uint2*)alloc((size_t)E * 8);
  float* dinv = (float*)alloc((size_t)N * 4);
  float* B0   = (float*)alloc((size_t)N * 32 * 4);
  float* B1   = (float*)alloc((size_t)N * 32 * 4);
  float* stats = (float*)alloc(3 * 64 * 4);
  float* ss    = (float*)alloc(3 * 64 * 4);
  float* pool  = (float*)alloc(512 * 32 * 4);

  hipMemsetAsync(cnt, 0, (size_t)N * 4, stream);
  hipMemsetAsync(stats, 0, 3 * 64 * 4, stream);

  const int nb_n = (N + TPB - 1) / TPB;
  const int nb_e = (E + TPB - 1) / TPB;
  const int nb_t = (N + 7) / 8;
  const int nb_scan = (N + SCAN_BLK - 1) / SCAN_BLK;
  const int total32 = N * 32;
  const float invN = 1.0f / (float)N;

  // ---- CSR build ----
  k_hist<<<nb_e, TPB, 0, stream>>>(col, cnt, E);
  k_scan_partial<<<nb_scan, SCAN_T, 0, stream>>>(cnt, bsum, N);
  k_scan_bsum<<<1, 1, 0, stream>>>(bsum, ptr + N, nb_scan, E);
  k_scan_final<<<nb_scan, SCAN_T, 0, stream>>>(cnt, bsum, ptr, cur, N);
  k_fill<<<nb_e, TPB, 0, stream>>>(row, col, ea, cur, pk, E);
  k_degdinv<<<nb_n, TPB, 0, stream>>>(pk, ptr, dinv, N);
  k_nrmcsr<<<nb_n, TPB, 0, stream>>>(pk, ptr, dinv, N);

  // ---- layer 0 (x[N,7] @ W0) ----
  k_transform<7, false><<<nb_t, TPB, 0, stream>>>(x, W0, nullptr, B0, N);
  k_gather<<<nb_t, TPB, 0, stream>>>(pk, ptr, dinv, B0, B1, N);
  k_stats<<<1024, TPB, 0, stream>>>(B1, stats, total32);
  k_bnfin<<<1, 32, 0, stream>>>(stats, bng, bnb, ss, invN);

  // ---- layer 1 ----
  k_transform<32, true><<<nb_t, TPB, 0, stream>>>(B1, W1, ss, B0, N);
  k_gather<<<nb_t, TPB, 0, stream>>>(pk, ptr, dinv, B0, B1, N);
  k_stats<<<1024, TPB, 0, stream>>>(B1, stats + 64, total32);
  k_bnfin<<<1, 32, 0, stream>>>(stats + 64, bng + 32, bnb + 32, ss + 64, invN);

  // ---- layer 2 ----
  k_transform<32, true><<<nb_t, TPB, 0, stream>>>(B1, W2, ss + 64, B0, N);
  k_gather<<<nb_t, TPB, 0, stream>>>(pk, ptr, dinv, B0, B1, N);
  k_stats<<<1024, TPB, 0, stream>>>(B1, stats + 128, total32);
  k_bnfin<<<1, 32, 0, stream>>>(stats + 128, bng + 64, bnb + 64, ss + 128, invN);

  // ---- layer 3 (no BN on output) ----
  k_transform<32, true><<<nb_t, TPB, 0, stream>>>(B1, W3, ss + 128, B0, N);
  k_gather<<<nb_t, TPB, 0, stream>>>(pk, ptr, dinv, B0, B1, N);

  // ---- pool + MLP head ----
  k_pool<<<512, TPB, 0, stream>>>(B1, batch, b3, pool, N);
  k_mlp<<<1, 512, 0, stream>>>(pool, Wm0, bm0, bnmg, bnmb, Wm1, bm1, out);
}

// Round 5
// 1260.764 us; speedup vs baseline: 1.2715x; 1.2237x over previous
//
#include <hip/hip_runtime.h>

#define TPB 256
constexpr float EPSV = 1e-5f;

// =================== CSR build (counting sort of edges by col) ===================

__global__ void k_hist(const int* __restrict__ col, int* __restrict__ cnt, int E) {
  int e = blockIdx.x * blockDim.x + threadIdx.x;
  if (e < E) atomicAdd(&cnt[col[e]], 1);
}

#define SCAN_T 512
#define SCAN_E 8
#define SCAN_BLK (SCAN_T * SCAN_E)  // 4096

__global__ void k_scan_partial(const int* __restrict__ cnt, int* __restrict__ bsum, int N) {
  __shared__ int red[SCAN_T];
  int tid = threadIdx.x;
  int base = blockIdx.x * SCAN_BLK + tid * SCAN_E;
  int s = 0;
#pragma unroll
  for (int k = 0; k < SCAN_E; ++k) {
    int i = base + k;
    if (i < N) s += cnt[i];
  }
  red[tid] = s;
  __syncthreads();
  for (int off = SCAN_T / 2; off > 0; off >>= 1) {
    if (tid < off) red[tid] += red[tid + off];
    __syncthreads();
  }
  if (tid == 0) bsum[blockIdx.x] = red[0];
}

__global__ void k_scan_bsum(int* __restrict__ bsum, int* __restrict__ ptrN, int nb, int E) {
  if (threadIdx.x == 0) {
    int run = 0;
    for (int b = 0; b < nb; ++b) { int v = bsum[b]; bsum[b] = run; run += v; }
    *ptrN = E;  // ptr[N]
  }
}

__global__ void k_scan_final(const int* __restrict__ cnt, const int* __restrict__ bsum,
                             int* __restrict__ ptr, int* __restrict__ cur, int N) {
  __shared__ int red[SCAN_T];
  int tid = threadIdx.x;
  int base = blockIdx.x * SCAN_BLK + tid * SCAN_E;
  int loc[SCAN_E];
  int s = 0;
#pragma unroll
  for (int k = 0; k < SCAN_E; ++k) {
    int i = base + k;
    int v = (i < N) ? cnt[i] : 0;
    loc[k] = s;
    s += v;
  }
  red[tid] = s;
  __syncthreads();
  for (int off = 1; off < SCAN_T; off <<= 1) {
    int v = (tid >= off) ? red[tid - off] : 0;
    __syncthreads();
    red[tid] += v;
    __syncthreads();
  }
  int tbase = bsum[blockIdx.x] + (tid > 0 ? red[tid - 1] : 0);
#pragma unroll
  for (int k = 0; k < SCAN_E; ++k) {
    int i = base + k;
    if (i < N) { int v = tbase + loc[k]; ptr[i] = v; cur[i] = v; }
  }
}

__global__ void k_fill(const int* __restrict__ row, const int* __restrict__ col,
                       const float* __restrict__ w, int* __restrict__ cur,
                       uint2* __restrict__ pk, int E) {
  int e = blockIdx.x * blockDim.x + threadIdx.x;
  if (e < E) {
    int pos = atomicAdd(&cur[col[e]], 1);
    pk[pos] = make_uint2((unsigned)row[e], __float_as_uint(w[e]));
  }
}

// deg[i] = 1 (self-loop) + sum of incoming weights; dinv = rsqrt
__global__ void k_degdinv(const uint2* __restrict__ pk, const int* __restrict__ ptr,
                          float* __restrict__ dinv, int N) {
  int i = blockIdx.x * blockDim.x + threadIdx.x;
  if (i >= N) return;
  int p0 = ptr[i], p1 = ptr[i + 1];
  float d = 1.0f;
  for (int p = p0; p < p1; ++p) d += __uint_as_float(pk[p].y);
  dinv[i] = d > 0.0f ? rsqrtf(fmaxf(d, EPSV)) : 0.0f;
}

// overwrite packed weight with norm = dinv[row]*w*dinv[col]
__global__ void k_nrmcsr(uint2* __restrict__ pk, const int* __restrict__ ptr,
                         const float* __restrict__ dinv, int N) {
  int i = blockIdx.x * blockDim.x + threadIdx.x;
  if (i >= N) return;
  int p0 = ptr[i], p1 = ptr[i + 1];
  float dvc = dinv[i];
  for (int p = p0; p < p1; ++p) {
    uint2 e = pk[p];
    pk[p].y = __float_as_uint(dinv[e.x] * __uint_as_float(e.y) * dvc);
  }
}

// =================== per-layer transform: t = relu(BN(in)) @ W ===================
// 8 nodes per block, 32 lanes per node (lane = output channel).

template <int IN, bool BN>
__global__ void k_transform(const float* __restrict__ in, const float* __restrict__ W,
                            const float* __restrict__ ss, float* __restrict__ t, int N) {
  __shared__ float Ws[IN * 32];
  __shared__ float hs[8 * IN];
  const int tid = threadIdx.x;
  const int n0 = blockIdx.x * 8;
  for (int k = tid; k < IN * 32; k += TPB) Ws[k] = W[k];
  for (int k = tid; k < 8 * IN; k += TPB) {
    int node = n0 + k / IN;
    float v = 0.0f;
    if (node < N) {
      v = in[n0 * IN + k];
      if constexpr (BN) {
        int c = k % IN;  // IN == 32 when BN
        v = fmaxf(v * ss[c] + ss[32 + c], 0.0f);
      }
    }
    hs[k] = v;
  }
  __syncthreads();
  const int j = tid >> 5, c = tid & 31;
  const int node = n0 + j;
  if (node < N) {
    float acc = 0.0f;
#pragma unroll
    for (int k = 0; k < IN; ++k) acc += hs[j * IN + k] * Ws[k * 32 + c];
    t[(size_t)node * 32 + c] = acc;
  }
}

// =================== CSR gather: out[n] = dinv[n]^2*t[n] + sum nrm*t[row] ===================

__global__ void k_gather(const uint2* __restrict__ pk, const int* __restrict__ ptr,
                         const float* __restrict__ dinv, const float* __restrict__ t,
                         float* __restrict__ out, int N) {
  const int tid = threadIdx.x;
  const int j = tid >> 5, c = tid & 31;
  const int n = blockIdx.x * 8 + j;
  if (n >= N) return;
  const int p0 = ptr[n], p1 = ptr[n + 1];
  const float dvn = dinv[n];
  float acc = dvn * dvn * t[(size_t)n * 32 + c];
  int p = p0;
  // unroll by 2 to keep more loads in flight
  for (; p + 1 < p1; p += 2) {
    uint2 e0 = pk[p], e1 = pk[p + 1];
    float v0 = t[(size_t)e0.x * 32 + c];
    float v1 = t[(size_t)e1.x * 32 + c];
    acc += __uint_as_float(e0.y) * v0;
    acc += __uint_as_float(e1.y) * v1;
  }
  if (p < p1) {
    uint2 e0 = pk[p];
    acc += __uint_as_float(e0.y) * t[(size_t)e0.x * 32 + c];
  }
  out[(size_t)n * 32 + c] = acc;
}

// =================== BN stats over node axis ===================

__global__ void k_stats(const float* __restrict__ x, float* __restrict__ gstats, int total) {
  __shared__ float ls[TPB], lq[TPB];
  int tid = threadIdx.x;
  float s = 0.f, q = 0.f;
  for (int idx = blockIdx.x * TPB + tid; idx < total; idx += gridDim.x * TPB) {
    float v = x[idx];
    s += v;
    q += v * v;
  }
  ls[tid] = s; lq[tid] = q;
  __syncthreads();
  for (int off = TPB / 2; off >= 32; off >>= 1) {
    if (tid < off) { ls[tid] += ls[tid + off]; lq[tid] += lq[tid + off]; }
    __syncthreads();
  }
  if (tid < 32) {
    unsafeAtomicAdd(&gstats[tid], ls[tid]);
    unsafeAtomicAdd(&gstats[32 + tid], lq[tid]);
  }
}

__global__ void k_bnfin(const float* __restrict__ gstats, const float* __restrict__ gamma,
                        const float* __restrict__ beta, float* __restrict__ ss, float invN) {
  int c = threadIdx.x;
  if (c < 32) {
    float m = gstats[c] * invN;
    float v = gstats[32 + c] * invN - m * m;
    float sc = gamma[c] * rsqrtf(v + EPSV);
    ss[c] = sc;
    ss[32 + c] = beta[c] - m * sc;
  }
}

// =================== global add pool (batch is sorted) ===================

__global__ void k_pool(const float* __restrict__ h, const int* __restrict__ batch,
                       const float* __restrict__ b3, float* __restrict__ pool, int N) {
  __shared__ float red[TPB];
  int g = blockIdx.x, tid = threadIdx.x;
  int lo = 0, hi = N;
  while (lo < hi) { int mid = (lo + hi) >> 1; if (batch[mid] < g) lo = mid + 1; else hi = mid; }
  int start = lo;
  hi = N;
  while (lo < hi) { int mid = (lo + hi) >> 1; if (batch[mid] < g + 1) lo = mid + 1; else hi = mid; }
  int end = lo;
  int j = tid >> 5, c = tid & 31;
  float acc = 0.f;
  for (int i = start + j; i < end; i += 8) acc += h[(size_t)i * 32 + c];
  red[tid] = acc;
  __syncthreads();
  for (int off = 128; off >= 32; off >>= 1) {
    if (tid < off) red[tid] += red[tid + off];
    __syncthreads();
  }
  if (tid < 32) pool[g * 32 + tid] = red[tid] + (float)(end - start) * b3[tid];
}

// =================== MLP head, stage 1: z = pool@Wm0+bm0 + BN stats ===================
// 8 rows/block, thread (j,c) computes one z element in a single scalar register.
// No per-thread arrays anywhere -> nothing to spill (the single-block k_mlp
// variants spilled 1.6-2 MB to scratch and serialized on one CU: 244-360 us).

__global__ void k_mlpz(const float* __restrict__ pool, const float* __restrict__ Wm0,
                       const float* __restrict__ bm0, float* __restrict__ z,
                       float* __restrict__ mstats) {
  __shared__ float Ws[32 * 32];
  __shared__ float ps[8 * 32];
  __shared__ float ls[TPB], lq[TPB];
  const int tid = threadIdx.x;
  const int g0 = blockIdx.x * 8;
  for (int k = tid; k < 1024; k += TPB) Ws[k] = Wm0[k];
  if (tid < 256) ps[tid] = pool[g0 * 32 + tid];
  __syncthreads();
  const int j = tid >> 5, c = tid & 31;
  float acc = bm0[c];
#pragma unroll
  for (int k = 0; k < 32; ++k) acc += ps[j * 32 + k] * Ws[k * 32 + c];
  z[(g0 + j) * 32 + c] = acc;
  ls[tid] = acc;
  lq[tid] = acc * acc;
  __syncthreads();
  for (int off = 128; off >= 32; off >>= 1) {
    if (tid < off) { ls[tid] += ls[tid + off]; lq[tid] += lq[tid + off]; }
    __syncthreads();
  }
  if (tid < 32) {
    unsafeAtomicAdd(&mstats[tid], ls[tid]);
    unsafeAtomicAdd(&mstats[32 + tid], lq[tid]);
  }
}

// =================== MLP head, stage 2: BN+relu+final matmul ===================
// 1024 threads: thread t -> (graph g = t>>1, output o = t&1). 32-iter loop,
// scalar accumulator, z is L2/LLC-hot.

__global__ void k_mlpfin(const float* __restrict__ z, const float* __restrict__ mstats,
                         const float* __restrict__ bng, const float* __restrict__ bnb,
                         const float* __restrict__ Wm1, const float* __restrict__ bm1,
                         float* __restrict__ out) {
  __shared__ float sc[32], sh[32], w1[64];
  const int tid = threadIdx.x;
  if (tid < 32) {
    float m = mstats[tid] * (1.0f / 512.0f);
    float v = mstats[32 + tid] * (1.0f / 512.0f) - m * m;
    float s = bng[tid] * rsqrtf(v + EPSV);
    sc[tid] = s;
    sh[tid] = bnb[tid] - m * s;
  }
  if (tid < 64) w1[tid] = Wm1[tid];
  __syncthreads();
  const int g = tid >> 1, o = tid & 1;
  float acc = bm1[o];
#pragma unroll
  for (int c = 0; c < 32; ++c) {
    float hc = fmaxf(z[g * 32 + c] * sc[c] + sh[c], 0.f);
    acc += hc * w1[c * 2 + o];
  }
  out[tid] = acc;
}

// =================== launch ===================

extern "C" void kernel_launch(void* const* d_in, const int* in_sizes, int n_in,
                              void* d_out, int out_size, void* d_ws, size_t ws_size,
                              hipStream_t stream) {
  const float* x     = (const float*)d_in[0];
  const int*   ei    = (const int*)d_in[1];
  const float* ea    = (const float*)d_in[2];
  const int*   batch = (const int*)d_in[3];
  const float* W0    = (const float*)d_in[4];
  const float* W1    = (const float*)d_in[6];
  const float* W2    = (const float*)d_in[8];
  const float* W3    = (const float*)d_in[10];
  const float* b3    = (const float*)d_in[11];
  const float* bng   = (const float*)d_in[12];  // [3,32]
  const float* bnb   = (const float*)d_in[13];
  const float* Wm0   = (const float*)d_in[14];
  const float* bm0   = (const float*)d_in[15];
  const float* bnmg  = (const float*)d_in[16];
  const float* bnmb  = (const float*)d_in[17];
  const float* Wm1   = (const float*)d_in[18];
  const float* bm1   = (const float*)d_in[19];
  float* out = (float*)d_out;

  const int N = in_sizes[3];
  const int E = in_sizes[2];
  const int* row = ei;
  const int* col = ei + E;

  char* wsb = (char*)d_ws;
  auto alloc = [&](size_t bytes) { char* p = wsb; wsb += (bytes + 255) & ~size_t(255); return p; };
  int*   cnt  = (int*)alloc((size_t)(N + 1) * 4);
  int*   ptr  = (int*)alloc((size_t)(N + 1) * 4);
  int*   cur  = (int*)alloc((size_t)N * 4);
  int*   bsum = (int*)alloc(1024 * 4);
  uint2* pk   = (uint2*)alloc((size_t)E * 8);
  float* dinv = (float*)alloc((size_t)N * 4);
  float* B0   = (float*)alloc((size_t)N * 32 * 4);
  float* B1   = (float*)alloc((size_t)N * 32 * 4);
  float* stats = (float*)alloc(4 * 64 * 4);   // 3 conv layers + MLP
  float* ss    = (float*)alloc(3 * 64 * 4);
  float* pool  = (float*)alloc(512 * 32 * 4);
  float* zbuf  = (float*)alloc(512 * 32 * 4);

  hipMemsetAsync(cnt, 0, (size_t)N * 4, stream);
  hipMemsetAsync(stats, 0, 4 * 64 * 4, stream);

  const int nb_n = (N + TPB - 1) / TPB;
  const int nb_e = (E + TPB - 1) / TPB;
  const int nb_t = (N + 7) / 8;
  const int nb_scan = (N + SCAN_BLK - 1) / SCAN_BLK;
  const int total32 = N * 32;
  const float invN = 1.0f / (float)N;
  float* mstats = stats + 192;

  // ---- CSR build ----
  k_hist<<<nb_e, TPB, 0, stream>>>(col, cnt, E);
  k_scan_partial<<<nb_scan, SCAN_T, 0, stream>>>(cnt, bsum, N);
  k_scan_bsum<<<1, 1, 0, stream>>>(bsum, ptr + N, nb_scan, E);
  k_scan_final<<<nb_scan, SCAN_T, 0, stream>>>(cnt, bsum, ptr, cur, N);
  k_fill<<<nb_e, TPB, 0, stream>>>(row, col, ea, cur, pk, E);
  k_degdinv<<<nb_n, TPB, 0, stream>>>(pk, ptr, dinv, N);
  k_nrmcsr<<<nb_n, TPB, 0, stream>>>(pk, ptr, dinv, N);

  // ---- layer 0 (x[N,7] @ W0) ----
  k_transform<7, false><<<nb_t, TPB, 0, stream>>>(x, W0, nullptr, B0, N);
  k_gather<<<nb_t, TPB, 0, stream>>>(pk, ptr, dinv, B0, B1, N);
  k_stats<<<1024, TPB, 0, stream>>>(B1, stats, total32);
  k_bnfin<<<1, 32, 0, stream>>>(stats, bng, bnb, ss, invN);

  // ---- layer 1 ----
  k_transform<32, true><<<nb_t, TPB, 0, stream>>>(B1, W1, ss, B0, N);
  k_gather<<<nb_t, TPB, 0, stream>>>(pk, ptr, dinv, B0, B1, N);
  k_stats<<<1024, TPB, 0, stream>>>(B1, stats + 64, total32);
  k_bnfin<<<1, 32, 0, stream>>>(stats + 64, bng + 32, bnb + 32, ss + 64, invN);

  // ---- layer 2 ----
  k_transform<32, true><<<nb_t, TPB, 0, stream>>>(B1, W2, ss + 64, B0, N);
  k_gather<<<nb_t, TPB, 0, stream>>>(pk, ptr, dinv, B0, B1, N);
  k_stats<<<1024, TPB, 0, stream>>>(B1, stats + 128, total32);
  k_bnfin<<<1, 32, 0, stream>>>(stats + 128, bng + 64, bnb + 64, ss + 128, invN);

  // ---- layer 3 (no BN on output) ----
  k_transform<32, true><<<nb_t, TPB, 0, stream>>>(B1, W3, ss + 128, B0, N);
  k_gather<<<nb_t, TPB, 0, stream>>>(pk, ptr, dinv, B0, B1, N);

  // ---- pool + MLP head ----
  k_pool<<<512, TPB, 0, stream>>>(B1, batch, b3, pool, N);
  k_mlpz<<<64, TPB, 0, stream>>>(pool, Wm0, bm0, zbuf, mstats);
  k_mlpfin<<<1, 1024, 0, stream>>>(zbuf, mstats, bnmg, bnmb, Wm1, bm1, out);
}

// Round 6
// 1064.681 us; speedup vs baseline: 1.5057x; 1.1842x over previous
//
#include <hip/hip_runtime.h>

#define TPB 256
#define RBITS 10               // bucket = node >> 10 (1024 nodes/bucket)
#define RSZ   1024
#define BMAX  512              // max buckets supported (N <= 512K)
#define CHUNK 4096             // edges per block in bucket passes
constexpr float EPSV = 1e-5f;

// =================== bucket-sorted CSR build ===================
// Replaces global-atomic hist + N-wide scan + random-scatter fill (k_fill was
// 193 us with 159 MB WRITE for a 20 MB payload: 8x line amplification from
// random 8B stores). Two-level: bin edges by 1024-node bucket with LDS
// histograms + run reservation (near-line-sized runs), then counting-sort
// each bucket in LDS into the final CSR segment (dense 50 KB region -> amp~1).

__global__ void k_bcnt(const int* __restrict__ col, int* __restrict__ bcnt, int E, int B) {
  __shared__ int h[BMAX];
  const int tid = threadIdx.x;
  for (int i = tid; i < B; i += TPB) h[i] = 0;
  __syncthreads();
  const int e0 = blockIdx.x * CHUNK;
  for (int k = tid; k < CHUNK; k += TPB) {
    int i = e0 + k;
    if (i < E) atomicAdd(&h[col[i] >> RBITS], 1);
  }
  __syncthreads();
  for (int i = tid; i < B; i += TPB)
    if (h[i]) atomicAdd(&bcnt[i], h[i]);
}

__global__ void k_bscan(const int* __restrict__ bcnt, int* __restrict__ bbase,
                        int* __restrict__ bcur, int B, int E) {
  __shared__ int red[BMAX];
  const int tid = threadIdx.x;  // 512 threads
  int v = (tid < B) ? bcnt[tid] : 0;
  red[tid] = v;
  __syncthreads();
  for (int off = 1; off < BMAX; off <<= 1) {
    int u = (tid >= off) ? red[tid - off] : 0;
    __syncthreads();
    red[tid] += u;
    __syncthreads();
  }
  int excl = red[tid] - v;
  if (tid < B) { bbase[tid] = excl; bcur[tid] = excl; }
  if (tid == 0) bbase[B] = E;
}

// bin edges into bucket-grouped buck[]: .x = row | (localcol<<19), .y = w bits
__global__ void k_binfill(const int* __restrict__ row, const int* __restrict__ col,
                          const float* __restrict__ w, int* __restrict__ bcur,
                          uint2* __restrict__ buck, int E, int B) {
  __shared__ int h[BMAX], base[BMAX], cur[BMAX];
  const int tid = threadIdx.x;
  for (int i = tid; i < B; i += TPB) { h[i] = 0; cur[i] = 0; }
  __syncthreads();
  const int e0 = blockIdx.x * CHUNK;
  for (int k = tid; k < CHUNK; k += TPB) {
    int i = e0 + k;
    if (i < E) atomicAdd(&h[col[i] >> RBITS], 1);
  }
  __syncthreads();
  for (int i = tid; i < B; i += TPB)
    base[i] = h[i] ? atomicAdd(&bcur[i], h[i]) : 0;
  __syncthreads();
  for (int k = tid; k < CHUNK; k += TPB) {
    int i = e0 + k;
    if (i >= E) continue;
    int c = col[i];
    int b = c >> RBITS;
    int pos = base[b] + atomicAdd(&cur[b], 1);
    unsigned lc = (unsigned)(c & (RSZ - 1));
    buck[pos] = make_uint2((unsigned)row[i] | (lc << 19), __float_as_uint(w[i]));
  }
}

// per-bucket counting sort -> final CSR (pk, ptr) + dinv for the bucket's nodes
__global__ __launch_bounds__(256) void k_bucket(const uint2* __restrict__ buck,
                                                const int* __restrict__ bbase,
                                                int* __restrict__ ptr, float* __restrict__ dinv,
                                                uint2* __restrict__ pk, int N, int E) {
  __shared__ int cnt[RSZ];
  __shared__ float wsum[RSZ];
  __shared__ int lofs[RSZ];
  __shared__ int red[256];
  const int bk = blockIdx.x, tid = threadIdx.x;
  const int n0 = bk << RBITS;
  const int nloc = min(RSZ, N - n0);
  for (int i = tid; i < RSZ; i += 256) { cnt[i] = 0; wsum[i] = 0.f; }
  __syncthreads();
  const int e0 = bbase[bk], e1 = bbase[bk + 1];
  for (int i = e0 + tid; i < e1; i += 256) {
    uint2 e = buck[i];
    int lc = e.x >> 19;
    atomicAdd(&cnt[lc], 1);
    atomicAdd(&wsum[lc], __uint_as_float(e.y));
  }
  __syncthreads();
  // scan cnt[1024]: thread t owns cnt[4t..4t+3]
  int a = cnt[tid * 4], b = cnt[tid * 4 + 1], c = cnt[tid * 4 + 2], d = cnt[tid * 4 + 3];
  int l1 = a, l2 = a + b, l3 = a + b + c, s = a + b + c + d;
  red[tid] = s;
  __syncthreads();
  for (int off = 1; off < 256; off <<= 1) {
    int u = (tid >= off) ? red[tid - off] : 0;
    __syncthreads();
    red[tid] += u;
    __syncthreads();
  }
  int tb = red[tid] - s;
  lofs[tid * 4] = tb; lofs[tid * 4 + 1] = tb + l1;
  lofs[tid * 4 + 2] = tb + l2; lofs[tid * 4 + 3] = tb + l3;
  __syncthreads();
  for (int i = tid; i < nloc; i += 256) {
    ptr[n0 + i] = e0 + lofs[i];
    dinv[n0 + i] = rsqrtf(1.0f + wsum[i]);  // deg >= 1 (self-loop), matches ref
  }
  for (int i = tid; i < RSZ; i += 256) cnt[i] = 0;
  __syncthreads();
  for (int i = e0 + tid; i < e1; i += 256) {
    uint2 e = buck[i];
    int lc = e.x >> 19;
    int pos = e0 + lofs[lc] + atomicAdd(&cnt[lc], 1);
    pk[pos] = make_uint2(e.x & 524287u, e.y);
  }
  if (bk == 0 && tid == 0) ptr[N] = E;
}

// overwrite packed weight with norm = dinv[row]*w*dinv[col]
__global__ void k_nrmcsr(uint2* __restrict__ pk, const int* __restrict__ ptr,
                         const float* __restrict__ dinv, int N) {
  int i = blockIdx.x * blockDim.x + threadIdx.x;
  if (i >= N) return;
  int p0 = ptr[i], p1 = ptr[i + 1];
  float dvc = dinv[i];
  for (int p = p0; p < p1; ++p) {
    uint2 e = pk[p];
    pk[p].y = __float_as_uint(dinv[e.x] * __uint_as_float(e.y) * dvc);
  }
}

// =================== per-layer transform: t = relu(BN(in)) @ W ===================

template <int IN, bool BN>
__global__ void k_transform(const float* __restrict__ in, const float* __restrict__ W,
                            const float* __restrict__ ss, float* __restrict__ t, int N) {
  __shared__ float Ws[IN * 32];
  __shared__ float hs[8 * IN];
  const int tid = threadIdx.x;
  const int n0 = blockIdx.x * 8;
  for (int k = tid; k < IN * 32; k += TPB) Ws[k] = W[k];
  for (int k = tid; k < 8 * IN; k += TPB) {
    int node = n0 + k / IN;
    float v = 0.0f;
    if (node < N) {
      v = in[n0 * IN + k];
      if constexpr (BN) {
        int c = k % IN;
        v = fmaxf(v * ss[c] + ss[32 + c], 0.0f);
      }
    }
    hs[k] = v;
  }
  __syncthreads();
  const int j = tid >> 5, c = tid & 31;
  const int node = n0 + j;
  if (node < N) {
    float acc = 0.0f;
#pragma unroll
    for (int k = 0; k < IN; ++k) acc += hs[j * IN + k] * Ws[k * 32 + c];
    t[(size_t)node * 32 + c] = acc;
  }
}

// =================== CSR gather ===================

__global__ void k_gather(const uint2* __restrict__ pk, const int* __restrict__ ptr,
                         const float* __restrict__ dinv, const float* __restrict__ t,
                         float* __restrict__ out, int N) {
  const int tid = threadIdx.x;
  const int j = tid >> 5, c = tid & 31;
  const int n = blockIdx.x * 8 + j;
  if (n >= N) return;
  const int p0 = ptr[n], p1 = ptr[n + 1];
  const float dvn = dinv[n];
  float acc = dvn * dvn * t[(size_t)n * 32 + c];
  int p = p0;
  for (; p + 1 < p1; p += 2) {
    uint2 e0 = pk[p], e1 = pk[p + 1];
    float v0 = t[(size_t)e0.x * 32 + c];
    float v1 = t[(size_t)e1.x * 32 + c];
    acc += __uint_as_float(e0.y) * v0;
    acc += __uint_as_float(e1.y) * v1;
  }
  if (p < p1) {
    uint2 e0 = pk[p];
    acc += __uint_as_float(e0.y) * t[(size_t)e0.x * 32 + c];
  }
  out[(size_t)n * 32 + c] = acc;
}

// =================== BN stats over node axis ===================

__global__ void k_stats(const float* __restrict__ x, float* __restrict__ gstats, int total) {
  __shared__ float ls[TPB], lq[TPB];
  int tid = threadIdx.x;
  float s = 0.f, q = 0.f;
  for (int idx = blockIdx.x * TPB + tid; idx < total; idx += gridDim.x * TPB) {
    float v = x[idx];
    s += v;
    q += v * v;
  }
  ls[tid] = s; lq[tid] = q;
  __syncthreads();
  for (int off = TPB / 2; off >= 32; off >>= 1) {
    if (tid < off) { ls[tid] += ls[tid + off]; lq[tid] += lq[tid + off]; }
    __syncthreads();
  }
  if (tid < 32) {
    unsafeAtomicAdd(&gstats[tid], ls[tid]);
    unsafeAtomicAdd(&gstats[32 + tid], lq[tid]);
  }
}

__global__ void k_bnfin(const float* __restrict__ gstats, const float* __restrict__ gamma,
                        const float* __restrict__ beta, float* __restrict__ ss, float invN) {
  int c = threadIdx.x;
  if (c < 32) {
    float m = gstats[c] * invN;
    float v = gstats[32 + c] * invN - m * m;
    float sc = gamma[c] * rsqrtf(v + EPSV);
    ss[c] = sc;
    ss[32 + c] = beta[c] - m * sc;
  }
}

// =================== global add pool (batch is sorted) ===================

__global__ void k_pool(const float* __restrict__ h, const int* __restrict__ batch,
                       const float* __restrict__ b3, float* __restrict__ pool, int N) {
  __shared__ float red[TPB];
  int g = blockIdx.x, tid = threadIdx.x;
  int lo = 0, hi = N;
  while (lo < hi) { int mid = (lo + hi) >> 1; if (batch[mid] < g) lo = mid + 1; else hi = mid; }
  int start = lo;
  hi = N;
  while (lo < hi) { int mid = (lo + hi) >> 1; if (batch[mid] < g + 1) lo = mid + 1; else hi = mid; }
  int end = lo;
  int j = tid >> 5, c = tid & 31;
  float acc = 0.f;
  for (int i = start + j; i < end; i += 8) acc += h[(size_t)i * 32 + c];
  red[tid] = acc;
  __syncthreads();
  for (int off = 128; off >= 32; off >>= 1) {
    if (tid < off) red[tid] += red[tid + off];
    __syncthreads();
  }
  if (tid < 32) pool[g * 32 + tid] = red[tid] + (float)(end - start) * b3[tid];
}

// =================== MLP head ===================

__global__ void k_mlpz(const float* __restrict__ pool, const float* __restrict__ Wm0,
                       const float* __restrict__ bm0, float* __restrict__ z,
                       float* __restrict__ mstats) {
  __shared__ float Ws[32 * 32];
  __shared__ float ps[8 * 32];
  __shared__ float ls[TPB], lq[TPB];
  const int tid = threadIdx.x;
  const int g0 = blockIdx.x * 8;
  for (int k = tid; k < 1024; k += TPB) Ws[k] = Wm0[k];
  if (tid < 256) ps[tid] = pool[g0 * 32 + tid];
  __syncthreads();
  const int j = tid >> 5, c = tid & 31;
  float acc = bm0[c];
#pragma unroll
  for (int k = 0; k < 32; ++k) acc += ps[j * 32 + k] * Ws[k * 32 + c];
  z[(g0 + j) * 32 + c] = acc;
  ls[tid] = acc;
  lq[tid] = acc * acc;
  __syncthreads();
  for (int off = 128; off >= 32; off >>= 1) {
    if (tid < off) { ls[tid] += ls[tid + off]; lq[tid] += lq[tid + off]; }
    __syncthreads();
  }
  if (tid < 32) {
    unsafeAtomicAdd(&mstats[tid], ls[tid]);
    unsafeAtomicAdd(&mstats[32 + tid], lq[tid]);
  }
}

__global__ void k_mlpfin(const float* __restrict__ z, const float* __restrict__ mstats,
                         const float* __restrict__ bng, const float* __restrict__ bnb,
                         const float* __restrict__ Wm1, const float* __restrict__ bm1,
                         float* __restrict__ out) {
  __shared__ float sc[32], sh[32], w1[64];
  const int tid = threadIdx.x;
  if (tid < 32) {
    float m = mstats[tid] * (1.0f / 512.0f);
    float v = mstats[32 + tid] * (1.0f / 512.0f) - m * m;
    float s = bng[tid] * rsqrtf(v + EPSV);
    sc[tid] = s;
    sh[tid] = bnb[tid] - m * s;
  }
  if (tid < 64) w1[tid] = Wm1[tid];
  __syncthreads();
  const int g = tid >> 1, o = tid & 1;
  float acc = bm1[o];
#pragma unroll
  for (int c = 0; c < 32; ++c) {
    float hc = fmaxf(z[g * 32 + c] * sc[c] + sh[c], 0.f);
    acc += hc * w1[c * 2 + o];
  }
  out[tid] = acc;
}

// =================== launch ===================

extern "C" void kernel_launch(void* const* d_in, const int* in_sizes, int n_in,
                              void* d_out, int out_size, void* d_ws, size_t ws_size,
                              hipStream_t stream) {
  const float* x     = (const float*)d_in[0];
  const int*   ei    = (const int*)d_in[1];
  const float* ea    = (const float*)d_in[2];
  const int*   batch = (const int*)d_in[3];
  const float* W0    = (const float*)d_in[4];
  const float* W1    = (const float*)d_in[6];
  const float* W2    = (const float*)d_in[8];
  const float* W3    = (const float*)d_in[10];
  const float* b3    = (const float*)d_in[11];
  const float* bng   = (const float*)d_in[12];  // [3,32]
  const float* bnb   = (const float*)d_in[13];
  const float* Wm0   = (const float*)d_in[14];
  const float* bm0   = (const float*)d_in[15];
  const float* bnmg  = (const float*)d_in[16];
  const float* bnmb  = (const float*)d_in[17];
  const float* Wm1   = (const float*)d_in[18];
  const float* bm1   = (const float*)d_in[19];
  float* out = (float*)d_out;

  const int N = in_sizes[3];
  const int E = in_sizes[2];
  const int* row = ei;
  const int* col = ei + E;
  const int B = (N + RSZ - 1) >> RBITS;  // buckets (391 for N=400000)

  char* wsb = (char*)d_ws;
  auto alloc = [&](size_t bytes) { char* p = wsb; wsb += (bytes + 255) & ~size_t(255); return p; };
  int*   bcnt  = (int*)alloc((size_t)(BMAX + 1) * 4);
  int*   bbase = (int*)alloc((size_t)(BMAX + 1) * 4);
  int*   bcur  = (int*)alloc((size_t)BMAX * 4);
  int*   ptr   = (int*)alloc((size_t)(N + 1) * 4);
  uint2* buck  = (uint2*)alloc((size_t)E * 8);
  uint2* pk    = (uint2*)alloc((size_t)E * 8);
  float* dinv  = (float*)alloc((size_t)N * 4);
  float* B0    = (float*)alloc((size_t)N * 32 * 4);
  float* B1    = (float*)alloc((size_t)N * 32 * 4);
  float* stats = (float*)alloc(4 * 64 * 4);   // 3 conv layers + MLP
  float* ss    = (float*)alloc(3 * 64 * 4);
  float* pool  = (float*)alloc(512 * 32 * 4);
  float* zbuf  = (float*)alloc(512 * 32 * 4);

  hipMemsetAsync(bcnt, 0, (size_t)(BMAX + 1) * 4, stream);
  hipMemsetAsync(stats, 0, 4 * 64 * 4, stream);

  const int nb_n = (N + TPB - 1) / TPB;
  const int nb_c = (E + CHUNK - 1) / CHUNK;
  const int nb_t = (N + 7) / 8;
  const int total32 = N * 32;
  const float invN = 1.0f / (float)N;
  float* mstats = stats + 192;

  // ---- CSR build (bucketed) ----
  k_bcnt<<<nb_c, TPB, 0, stream>>>(col, bcnt, E, B);
  k_bscan<<<1, BMAX, 0, stream>>>(bcnt, bbase, bcur, B, E);
  k_binfill<<<nb_c, TPB, 0, stream>>>(row, col, ea, bcur, buck, E, B);
  k_bucket<<<B, 256, 0, stream>>>(buck, bbase, ptr, dinv, pk, N, E);
  k_nrmcsr<<<nb_n, TPB, 0, stream>>>(pk, ptr, dinv, N);

  // ---- layer 0 (x[N,7] @ W0) ----
  k_transform<7, false><<<nb_t, TPB, 0, stream>>>(x, W0, nullptr, B0, N);
  k_gather<<<nb_t, TPB, 0, stream>>>(pk, ptr, dinv, B0, B1, N);
  k_stats<<<1024, TPB, 0, stream>>>(B1, stats, total32);
  k_bnfin<<<1, 32, 0, stream>>>(stats, bng, bnb, ss, invN);

  // ---- layer 1 ----
  k_transform<32, true><<<nb_t, TPB, 0, stream>>>(B1, W1, ss, B0, N);
  k_gather<<<nb_t, TPB, 0, stream>>>(pk, ptr, dinv, B0, B1, N);
  k_stats<<<1024, TPB, 0, stream>>>(B1, stats + 64, total32);
  k_bnfin<<<1, 32, 0, stream>>>(stats + 64, bng + 32, bnb + 32, ss + 64, invN);

  // ---- layer 2 ----
  k_transform<32, true><<<nb_t, TPB, 0, stream>>>(B1, W2, ss + 64, B0, N);
  k_gather<<<nb_t, TPB, 0, stream>>>(pk, ptr, dinv, B0, B1, N);
  k_stats<<<1024, TPB, 0, stream>>>(B1, stats + 128, total32);
  k_bnfin<<<1, 32, 0, stream>>>(stats + 128, bng + 64, bnb + 64, ss + 128, invN);

  // ---- layer 3 (no BN on output) ----
  k_transform<32, true><<<nb_t, TPB, 0, stream>>>(B1, W3, ss + 128, B0, N);
  k_gather<<<nb_t, TPB, 0, stream>>>(pk, ptr, dinv, B0, B1, N);

  // ---- pool + MLP head ----
  k_pool<<<512, TPB, 0, stream>>>(B1, batch, b3, pool, N);
  k_mlpz<<<64, TPB, 0, stream>>>(pool, Wm0, bm0, zbuf, mstats);
  k_mlpfin<<<1, 1024, 0, stream>>>(zbuf, mstats, bnmg, bnmb, Wm1, bm1, out);
}

// Round 7
// 1023.033 us; speedup vs baseline: 1.5670x; 1.0407x over previous
//
#include <hip/hip_runtime.h>

#define TPB 256
#define RBITS 10               // bucket = node >> 10 (1024 nodes/bucket)
#define RSZ   1024
#define BMAX  512              // max buckets supported (N <= 512K)
#define CHUNK 4096             // edges per block in bucket passes
constexpr float EPSV = 1e-5f;

// bf16 helpers (feature buffers are bf16: halves gather row payload; tolerance
// threshold is 4.7e-2, we run at ~4e-3 -> ample headroom)
__device__ __forceinline__ float bf2f(unsigned short u) {
  return __uint_as_float((unsigned)u << 16);
}
__device__ __forceinline__ unsigned short f2bf(float f) {
  unsigned u = __float_as_uint(f);
  return (unsigned short)((u + 0x7fffu + ((u >> 16) & 1u)) >> 16);  // RNE
}

// =================== bucket-sorted CSR build ===================

__global__ void k_bcnt(const int* __restrict__ col, int* __restrict__ bcnt, int E, int B) {
  __shared__ int h[BMAX];
  const int tid = threadIdx.x;
  for (int i = tid; i < B; i += TPB) h[i] = 0;
  __syncthreads();
  const int e0 = blockIdx.x * CHUNK;
  for (int k = tid; k < CHUNK; k += TPB) {
    int i = e0 + k;
    if (i < E) atomicAdd(&h[col[i] >> RBITS], 1);
  }
  __syncthreads();
  for (int i = tid; i < B; i += TPB)
    if (h[i]) atomicAdd(&bcnt[i], h[i]);
}

__global__ void k_bscan(const int* __restrict__ bcnt, int* __restrict__ bbase,
                        int* __restrict__ bcur, int B, int E) {
  __shared__ int red[BMAX];
  const int tid = threadIdx.x;  // 512 threads
  int v = (tid < B) ? bcnt[tid] : 0;
  red[tid] = v;
  __syncthreads();
  for (int off = 1; off < BMAX; off <<= 1) {
    int u = (tid >= off) ? red[tid - off] : 0;
    __syncthreads();
    red[tid] += u;
    __syncthreads();
  }
  int excl = red[tid] - v;
  if (tid < B) { bbase[tid] = excl; bcur[tid] = excl; }
  if (tid == 0) bbase[B] = E;
}

// bin edges into bucket-grouped buck[]: .x = row | (localcol<<19), .y = w bits
__global__ void k_binfill(const int* __restrict__ row, const int* __restrict__ col,
                          const float* __restrict__ w, int* __restrict__ bcur,
                          uint2* __restrict__ buck, int E, int B) {
  __shared__ int h[BMAX], base[BMAX], cur[BMAX];
  const int tid = threadIdx.x;
  for (int i = tid; i < B; i += TPB) { h[i] = 0; cur[i] = 0; }
  __syncthreads();
  const int e0 = blockIdx.x * CHUNK;
  for (int k = tid; k < CHUNK; k += TPB) {
    int i = e0 + k;
    if (i < E) atomicAdd(&h[col[i] >> RBITS], 1);
  }
  __syncthreads();
  for (int i = tid; i < B; i += TPB)
    base[i] = h[i] ? atomicAdd(&bcur[i], h[i]) : 0;
  __syncthreads();
  for (int k = tid; k < CHUNK; k += TPB) {
    int i = e0 + k;
    if (i >= E) continue;
    int c = col[i];
    int b = c >> RBITS;
    int pos = base[b] + atomicAdd(&cur[b], 1);
    unsigned lc = (unsigned)(c & (RSZ - 1));
    buck[pos] = make_uint2((unsigned)row[i] | (lc << 19), __float_as_uint(w[i]));
  }
}

// per-bucket counting sort -> final CSR (pk, ptr) + dinv for the bucket's nodes
__global__ __launch_bounds__(256) void k_bucket(const uint2* __restrict__ buck,
                                                const int* __restrict__ bbase,
                                                int* __restrict__ ptr, float* __restrict__ dinv,
                                                uint2* __restrict__ pk, int N, int E) {
  __shared__ int cnt[RSZ];
  __shared__ float wsum[RSZ];
  __shared__ int lofs[RSZ];
  __shared__ int red[256];
  const int bk = blockIdx.x, tid = threadIdx.x;
  const int n0 = bk << RBITS;
  const int nloc = min(RSZ, N - n0);
  for (int i = tid; i < RSZ; i += 256) { cnt[i] = 0; wsum[i] = 0.f; }
  __syncthreads();
  const int e0 = bbase[bk], e1 = bbase[bk + 1];
  for (int i = e0 + tid; i < e1; i += 256) {
    uint2 e = buck[i];
    int lc = e.x >> 19;
    atomicAdd(&cnt[lc], 1);
    atomicAdd(&wsum[lc], __uint_as_float(e.y));
  }
  __syncthreads();
  int a = cnt[tid * 4], b = cnt[tid * 4 + 1], c = cnt[tid * 4 + 2], d = cnt[tid * 4 + 3];
  int l1 = a, l2 = a + b, l3 = a + b + c, s = a + b + c + d;
  red[tid] = s;
  __syncthreads();
  for (int off = 1; off < 256; off <<= 1) {
    int u = (tid >= off) ? red[tid - off] : 0;
    __syncthreads();
    red[tid] += u;
    __syncthreads();
  }
  int tb = red[tid] - s;
  lofs[tid * 4] = tb; lofs[tid * 4 + 1] = tb + l1;
  lofs[tid * 4 + 2] = tb + l2; lofs[tid * 4 + 3] = tb + l3;
  __syncthreads();
  for (int i = tid; i < nloc; i += 256) {
    ptr[n0 + i] = e0 + lofs[i];
    dinv[n0 + i] = rsqrtf(1.0f + wsum[i]);  // deg >= 1 (self-loop)
  }
  for (int i = tid; i < RSZ; i += 256) cnt[i] = 0;
  __syncthreads();
  for (int i = e0 + tid; i < e1; i += 256) {
    uint2 e = buck[i];
    int lc = e.x >> 19;
    int pos = e0 + lofs[lc] + atomicAdd(&cnt[lc], 1);
    pk[pos] = make_uint2(e.x & 524287u, e.y);
  }
  if (bk == 0 && tid == 0) ptr[N] = E;
}

// overwrite packed weight with norm = dinv[row]*w*dinv[col]
__global__ void k_nrmcsr(uint2* __restrict__ pk, const int* __restrict__ ptr,
                         const float* __restrict__ dinv, int N) {
  int i = blockIdx.x * blockDim.x + threadIdx.x;
  if (i >= N) return;
  int p0 = ptr[i], p1 = ptr[i + 1];
  float dvc = dinv[i];
  for (int p = p0; p < p1; ++p) {
    uint2 e = pk[p];
    pk[p].y = __float_as_uint(dinv[e.x] * __uint_as_float(e.y) * dvc);
  }
}

// =================== transforms: t = relu(BN(in)) @ W  (bf16 out) ===================

// layer 0: f32 input [N,7]
__global__ void k_transform0(const float* __restrict__ in, const float* __restrict__ W,
                             unsigned short* __restrict__ t, int N) {
  __shared__ float Ws[7 * 32];
  __shared__ float hs[8 * 7];
  const int tid = threadIdx.x;
  const int n0 = blockIdx.x * 8;
  if (tid < 7 * 32) Ws[tid] = W[tid];
  if (tid < 8 * 7) {
    int node = n0 + tid / 7;
    hs[tid] = (node < N) ? in[n0 * 7 + tid] : 0.0f;
  }
  __syncthreads();
  const int j = tid >> 5, c = tid & 31;
  const int node = n0 + j;
  if (node < N) {
    float acc = 0.0f;
#pragma unroll
    for (int k = 0; k < 7; ++k) acc += hs[j * 7 + k] * Ws[k * 32 + c];
    t[(size_t)node * 32 + c] = f2bf(acc);
  }
}

// layers 1-3: bf16 input [N,32], BN+relu fused via ss
__global__ void k_transform(const unsigned short* __restrict__ in, const float* __restrict__ W,
                            const float* __restrict__ ss, unsigned short* __restrict__ t, int N) {
  __shared__ float Ws[32 * 32];
  __shared__ float hs[8 * 32];
  const int tid = threadIdx.x;
  const int n0 = blockIdx.x * 8;
  for (int k = tid; k < 1024; k += TPB) Ws[k] = W[k];
  {
    int node = n0 + (tid >> 5);
    int c = tid & 31;
    float v = 0.0f;
    if (node < N) {
      v = bf2f(in[(size_t)n0 * 32 + tid]);
      v = fmaxf(v * ss[c] + ss[32 + c], 0.0f);
    }
    hs[tid] = v;
  }
  __syncthreads();
  const int j = tid >> 5, c = tid & 31;
  const int node = n0 + j;
  if (node < N) {
    float acc = 0.0f;
#pragma unroll
    for (int k = 0; k < 32; ++k) acc += hs[j * 32 + k] * Ws[k * 32 + c];
    t[(size_t)node * 32 + c] = f2bf(acc);
  }
}

// =================== CSR gather (bf16 in/out) ===================

__global__ void k_gather(const uint2* __restrict__ pk, const int* __restrict__ ptr,
                         const float* __restrict__ dinv, const unsigned short* __restrict__ t,
                         unsigned short* __restrict__ out, int N) {
  const int tid = threadIdx.x;
  const int j = tid >> 5, c = tid & 31;
  const int n = blockIdx.x * 8 + j;
  if (n >= N) return;
  const int p0 = ptr[n], p1 = ptr[n + 1];
  const float dvn = dinv[n];
  float acc = dvn * dvn * bf2f(t[(size_t)n * 32 + c]);
  int p = p0;
  for (; p + 1 < p1; p += 2) {
    uint2 e0 = pk[p], e1 = pk[p + 1];
    float v0 = bf2f(t[(size_t)e0.x * 32 + c]);
    float v1 = bf2f(t[(size_t)e1.x * 32 + c]);
    acc += __uint_as_float(e0.y) * v0;
    acc += __uint_as_float(e1.y) * v1;
  }
  if (p < p1) {
    uint2 e0 = pk[p];
    acc += __uint_as_float(e0.y) * bf2f(t[(size_t)e0.x * 32 + c]);
  }
  out[(size_t)n * 32 + c] = f2bf(acc);
}

// =================== BN stats over node axis (bf16 in) ===================

__global__ void k_stats(const unsigned short* __restrict__ x, float* __restrict__ gstats,
                        int total) {
  __shared__ float ls[TPB], lq[TPB];
  int tid = threadIdx.x;
  float s = 0.f, q = 0.f;
  for (int idx = blockIdx.x * TPB + tid; idx < total; idx += gridDim.x * TPB) {
    float v = bf2f(x[idx]);
    s += v;
    q += v * v;
  }
  ls[tid] = s; lq[tid] = q;
  __syncthreads();
  for (int off = TPB / 2; off >= 32; off >>= 1) {
    if (tid < off) { ls[tid] += ls[tid + off]; lq[tid] += lq[tid + off]; }
    __syncthreads();
  }
  if (tid < 32) {
    unsafeAtomicAdd(&gstats[tid], ls[tid]);
    unsafeAtomicAdd(&gstats[32 + tid], lq[tid]);
  }
}

__global__ void k_bnfin(const float* __restrict__ gstats, const float* __restrict__ gamma,
                        const float* __restrict__ beta, float* __restrict__ ss, float invN) {
  int c = threadIdx.x;
  if (c < 32) {
    float m = gstats[c] * invN;
    float v = gstats[32 + c] * invN - m * m;
    float sc = gamma[c] * rsqrtf(v + EPSV);
    ss[c] = sc;
    ss[32 + c] = beta[c] - m * sc;
  }
}

// =================== global add pool (batch is sorted, bf16 in) ===================

__global__ void k_pool(const unsigned short* __restrict__ h, const int* __restrict__ batch,
                       const float* __restrict__ b3, float* __restrict__ pool, int N) {
  __shared__ float red[TPB];
  int g = blockIdx.x, tid = threadIdx.x;
  int lo = 0, hi = N;
  while (lo < hi) { int mid = (lo + hi) >> 1; if (batch[mid] < g) lo = mid + 1; else hi = mid; }
  int start = lo;
  hi = N;
  while (lo < hi) { int mid = (lo + hi) >> 1; if (batch[mid] < g + 1) lo = mid + 1; else hi = mid; }
  int end = lo;
  int j = tid >> 5, c = tid & 31;
  float acc = 0.f;
  for (int i = start + j; i < end; i += 8) acc += bf2f(h[(size_t)i * 32 + c]);
  red[tid] = acc;
  __syncthreads();
  for (int off = 128; off >= 32; off >>= 1) {
    if (tid < off) red[tid] += red[tid + off];
    __syncthreads();
  }
  if (tid < 32) pool[g * 32 + tid] = red[tid] + (float)(end - start) * b3[tid];
}

// =================== MLP head ===================

__global__ void k_mlpz(const float* __restrict__ pool, const float* __restrict__ Wm0,
                       const float* __restrict__ bm0, float* __restrict__ z,
                       float* __restrict__ mstats) {
  __shared__ float Ws[32 * 32];
  __shared__ float ps[8 * 32];
  __shared__ float ls[TPB], lq[TPB];
  const int tid = threadIdx.x;
  const int g0 = blockIdx.x * 8;
  for (int k = tid; k < 1024; k += TPB) Ws[k] = Wm0[k];
  if (tid < 256) ps[tid] = pool[g0 * 32 + tid];
  __syncthreads();
  const int j = tid >> 5, c = tid & 31;
  float acc = bm0[c];
#pragma unroll
  for (int k = 0; k < 32; ++k) acc += ps[j * 32 + k] * Ws[k * 32 + c];
  z[(g0 + j) * 32 + c] = acc;
  ls[tid] = acc;
  lq[tid] = acc * acc;
  __syncthreads();
  for (int off = 128; off >= 32; off >>= 1) {
    if (tid < off) { ls[tid] += ls[tid + off]; lq[tid] += lq[tid + off]; }
    __syncthreads();
  }
  if (tid < 32) {
    unsafeAtomicAdd(&mstats[tid], ls[tid]);
    unsafeAtomicAdd(&mstats[32 + tid], lq[tid]);
  }
}

__global__ void k_mlpfin(const float* __restrict__ z, const float* __restrict__ mstats,
                         const float* __restrict__ bng, const float* __restrict__ bnb,
                         const float* __restrict__ Wm1, const float* __restrict__ bm1,
                         float* __restrict__ out) {
  __shared__ float sc[32], sh[32], w1[64];
  const int tid = threadIdx.x;
  if (tid < 32) {
    float m = mstats[tid] * (1.0f / 512.0f);
    float v = mstats[32 + tid] * (1.0f / 512.0f) - m * m;
    float s = bng[tid] * rsqrtf(v + EPSV);
    sc[tid] = s;
    sh[tid] = bnb[tid] - m * s;
  }
  if (tid < 64) w1[tid] = Wm1[tid];
  __syncthreads();
  const int g = tid >> 1, o = tid & 1;
  float acc = bm1[o];
#pragma unroll
  for (int c = 0; c < 32; ++c) {
    float hc = fmaxf(z[g * 32 + c] * sc[c] + sh[c], 0.f);
    acc += hc * w1[c * 2 + o];
  }
  out[tid] = acc;
}

// =================== launch ===================

extern "C" void kernel_launch(void* const* d_in, const int* in_sizes, int n_in,
                              void* d_out, int out_size, void* d_ws, size_t ws_size,
                              hipStream_t stream) {
  const float* x     = (const float*)d_in[0];
  const int*   ei    = (const int*)d_in[1];
  const float* ea    = (const float*)d_in[2];
  const int*   batch = (const int*)d_in[3];
  const float* W0    = (const float*)d_in[4];
  const float* W1    = (const float*)d_in[6];
  const float* W2    = (const float*)d_in[8];
  const float* W3    = (const float*)d_in[10];
  const float* b3    = (const float*)d_in[11];
  const float* bng   = (const float*)d_in[12];  // [3,32]
  const float* bnb   = (const float*)d_in[13];
  const float* Wm0   = (const float*)d_in[14];
  const float* bm0   = (const float*)d_in[15];
  const float* bnmg  = (const float*)d_in[16];
  const float* bnmb  = (const float*)d_in[17];
  const float* Wm1   = (const float*)d_in[18];
  const float* bm1   = (const float*)d_in[19];
  float* out = (float*)d_out;

  const int N = in_sizes[3];
  const int E = in_sizes[2];
  const int* row = ei;
  const int* col = ei + E;
  const int B = (N + RSZ - 1) >> RBITS;

  char* wsb = (char*)d_ws;
  auto alloc = [&](size_t bytes) { char* p = wsb; wsb += (bytes + 255) & ~size_t(255); return p; };
  int*   bcnt  = (int*)alloc((size_t)(BMAX + 1) * 4);
  int*   bbase = (int*)alloc((size_t)(BMAX + 1) * 4);
  int*   bcur  = (int*)alloc((size_t)BMAX * 4);
  int*   ptr   = (int*)alloc((size_t)(N + 1) * 4);
  uint2* buck  = (uint2*)alloc((size_t)E * 8);
  uint2* pk    = (uint2*)alloc((size_t)E * 8);
  float* dinv  = (float*)alloc((size_t)N * 4);
  unsigned short* B0 = (unsigned short*)alloc((size_t)N * 32 * 2);  // bf16
  unsigned short* B1 = (unsigned short*)alloc((size_t)N * 32 * 2);  // bf16
  float* stats = (float*)alloc(4 * 64 * 4);
  float* ss    = (float*)alloc(3 * 64 * 4);
  float* pool  = (float*)alloc(512 * 32 * 4);
  float* zbuf  = (float*)alloc(512 * 32 * 4);

  hipMemsetAsync(bcnt, 0, (size_t)(BMAX + 1) * 4, stream);
  hipMemsetAsync(stats, 0, 4 * 64 * 4, stream);

  const int nb_n = (N + TPB - 1) / TPB;
  const int nb_c = (E + CHUNK - 1) / CHUNK;
  const int nb_t = (N + 7) / 8;
  const int total32 = N * 32;
  const float invN = 1.0f / (float)N;
  float* mstats = stats + 192;

  // ---- CSR build (bucketed) ----
  k_bcnt<<<nb_c, TPB, 0, stream>>>(col, bcnt, E, B);
  k_bscan<<<1, BMAX, 0, stream>>>(bcnt, bbase, bcur, B, E);
  k_binfill<<<nb_c, TPB, 0, stream>>>(row, col, ea, bcur, buck, E, B);
  k_bucket<<<B, 256, 0, stream>>>(buck, bbase, ptr, dinv, pk, N, E);
  k_nrmcsr<<<nb_n, TPB, 0, stream>>>(pk, ptr, dinv, N);

  // ---- layer 0 ----
  k_transform0<<<nb_t, TPB, 0, stream>>>(x, W0, B0, N);
  k_gather<<<nb_t, TPB, 0, stream>>>(pk, ptr, dinv, B0, B1, N);
  k_stats<<<1024, TPB, 0, stream>>>(B1, stats, total32);
  k_bnfin<<<1, 32, 0, stream>>>(stats, bng, bnb, ss, invN);

  // ---- layer 1 ----
  k_transform<<<nb_t, TPB, 0, stream>>>(B1, W1, ss, B0, N);
  k_gather<<<nb_t, TPB, 0, stream>>>(pk, ptr, dinv, B0, B1, N);
  k_stats<<<1024, TPB, 0, stream>>>(B1, stats + 64, total32);
  k_bnfin<<<1, 32, 0, stream>>>(stats + 64, bng + 32, bnb + 32, ss + 64, invN);

  // ---- layer 2 ----
  k_transform<<<nb_t, TPB, 0, stream>>>(B1, W2, ss + 64, B0, N);
  k_gather<<<nb_t, TPB, 0, stream>>>(pk, ptr, dinv, B0, B1, N);
  k_stats<<<1024, TPB, 0, stream>>>(B1, stats + 128, total32);
  k_bnfin<<<1, 32, 0, stream>>>(stats + 128, bng + 64, bnb + 64, ss + 128, invN);

  // ---- layer 3 (no BN on output) ----
  k_transform<<<nb_t, TPB, 0, stream>>>(B1, W3, ss + 128, B0, N);
  k_gather<<<nb_t, TPB, 0, stream>>>(pk, ptr, dinv, B0, B1, N);

  // ---- pool + MLP head ----
  k_pool<<<512, TPB, 0, stream>>>(B1, batch, b3, pool, N);
  k_mlpz<<<64, TPB, 0, stream>>>(pool, Wm0, bm0, zbuf, mstats);
  k_mlpfin<<<1, 1024, 0, stream>>>(zbuf, mstats, bnmg, bnmb, Wm1, bm1, out);
}